// Round 1
// baseline (150.773 us; speedup 1.0000x reference)
//
#include <hip/hip_runtime.h>

#define FV 128
#define NCLIN 38
#define NPIX 36
#define NTOT 74     // NCLIN + NPIX
#define BATCH 1024
#define HID 512
#define COMB 4992   // 39*128
#define XPAD 136    // LDS row stride in ushorts

typedef __attribute__((ext_vector_type(4))) float f32x4;
typedef __attribute__((ext_vector_type(8))) short s16x8;

// ws layout (float offsets):
//   WcT bf16 [0, 8192)           (W_self + W_msg/37)^T, [n][k]
//   WiT bf16 [8192, 16384)       (W_self + W_msg/39)^T
//   WmT bf16 [16384, 24576)      W_msg^T  (for t-vector MFMA)
//   combined [24576, 2580480)    bf16 (1024 x 4992)
//   W1T      [2580480, 3858432)  bf16 (512 x 4992)
//   z[8]     [3858432, 8052736)  fp32 partials, 8 x (1024 x 512)
#define WS_WCT  0
#define WS_WIT  8192
#define WS_WMT  16384
#define WS_COMB 24576
#define WS_W1T  2580480
#define WS_Z    3858432
#define ZSTRIDE (BATCH * HID)

__device__ __forceinline__ unsigned short bf16_rne(float f) {
    union { float f; unsigned int u; } v; v.f = f;
    unsigned int u = v.u;
    u += 0x7fffu + ((u >> 16) & 1u);
    return (unsigned short)(u >> 16);
}
__device__ __forceinline__ float bf2f(unsigned short h) {
    union { unsigned int u; float f; } v; v.u = ((unsigned int)h) << 16;
    return v.f;
}

// Static weight prep: W1 transpose->bf16 (blocks x<78) + Wc/Wi/Wm transpose (x==78).
__global__ __launch_bounds__(256) void k_static(
    const float* __restrict__ W1, const float* __restrict__ wself,
    const float* __restrict__ wmsg, float* __restrict__ ws)
{
    const int t = threadIdx.x;
    if (blockIdx.x == 78) {
        unsigned short* WcT = (unsigned short*)(ws + WS_WCT);
        unsigned short* WiT = (unsigned short*)(ws + WS_WIT);
        unsigned short* WmT = (unsigned short*)(ws + WS_WMT);
        const int r  = blockIdx.y * 16 + (t >> 4);
        const int f0 = (t & 15) * 8;
#pragma unroll
        for (int j = 0; j < 8; ++j) {
            const int f = f0 + j;
            const int idx = r * 128 + f;
            const float wm = wmsg[idx];
            const float s  = wself[idx];
            WcT[f * 128 + r] = bf16_rne(s + wm * (1.0f / 37.0f));
            WiT[f * 128 + r] = bf16_rne(s + wm * (1.0f / 39.0f));
            WmT[f * 128 + r] = bf16_rne(wm);
        }
        return;
    }
    unsigned short* W1T = (unsigned short*)(ws + WS_W1T);
    const int k0 = blockIdx.x * 64;
    const int n0 = blockIdx.y * 64;
    __shared__ float tile[64][65];
    const int r16 = t >> 4;
    const int c4  = (t & 15) * 4;
#pragma unroll
    for (int p = 0; p < 4; ++p) {
        const int r = p * 16 + r16;
        const float4 v = *(const float4*)&W1[(size_t)(k0 + r) * HID + n0 + c4];
        tile[r][c4 + 0] = v.x; tile[r][c4 + 1] = v.y;
        tile[r][c4 + 2] = v.z; tile[r][c4 + 3] = v.w;
    }
    __syncthreads();
    const int j  = t >> 2;
    const int i0 = (t & 3) * 16;
    unsigned short tmp[16];
#pragma unroll
    for (int s = 0; s < 16; ++s) tmp[s] = bf16_rne(tile[i0 + s][j]);
    unsigned short* dst = &W1T[(size_t)(n0 + j) * COMB + k0 + i0];
    *(uint4*)&dst[0] = *(uint4*)&tmp[0];
    *(uint4*)&dst[8] = *(uint4*)&tmp[8];
}

// Fused per-batch pipeline: stage x (bf16) -> feature sums -> t via MFMA ->
// MFMA node transform both phases -> combined (bf16).
__global__ __launch_bounds__(256) void k_batch(
    const float* __restrict__ clin, const float* __restrict__ img,
    const float* __restrict__ bg, float* __restrict__ ws)
{
    const int b = blockIdx.x;
    const int t = threadIdx.x;

    __shared__ __align__(16) unsigned short xl[NTOT * XPAD];
    __shared__ __align__(16) unsigned short sab[2 * 128]; // row0=S_img/37, row1=S_clin/39
    __shared__ float tcv[128];
    __shared__ float tiv[128];

    // ---- stage x as bf16 ----
    const float* xc = clin + (size_t)b * NCLIN * FV;
    const float* xi = img  + (size_t)b * NPIX * FV;
    for (int i = t; i < NCLIN * 32; i += 256) {
        const int row = i >> 5, c4 = (i & 31) * 4;
        const float4 v = *(const float4*)&xc[row * 128 + c4];
        ushort4 u;
        u.x = bf16_rne(v.x); u.y = bf16_rne(v.y);
        u.z = bf16_rne(v.z); u.w = bf16_rne(v.w);
        *(ushort4*)&xl[row * XPAD + c4] = u;
    }
    for (int i = t; i < NPIX * 32; i += 256) {
        const int row = i >> 5, c4 = (i & 31) * 4;
        const float4 v = *(const float4*)&xi[row * 128 + c4];
        ushort4 u;
        u.x = bf16_rne(v.x); u.y = bf16_rne(v.y);
        u.z = bf16_rne(v.z); u.w = bf16_rne(v.w);
        *(ushort4*)&xl[(NCLIN + row) * XPAD + c4] = u;
    }
    __syncthreads();

    // ---- feature sums -> sab (bf16) ----
    const int f = t & 127;
    if (t < 128) {
        float s = 0.f;
#pragma unroll
        for (int n = 0; n < NCLIN; ++n) s += bf2f(xl[n * XPAD + f]);
        sab[128 + f] = bf16_rne(s * (1.0f / 39.0f));
    } else {
        float s = 0.f;
#pragma unroll
        for (int n = 0; n < NPIX; ++n) s += bf2f(xl[(NCLIN + n) * XPAD + f]);
        sab[f] = bf16_rne(s * (1.0f / 37.0f));
    }
    __syncthreads();

    const int wave = t >> 6;
    const int lane = t & 63;
    const int l16  = lane & 15;
    const int q    = lane >> 4;
    const int n0   = wave * 32 + l16;

    // ---- t vectors via MFMA: T(2x128) = sab(2x128) @ W_msg ----
    {
        const unsigned short* WmT = (const unsigned short*)(ws + WS_WMT);
        const int am = (l16 < 2) ? l16 : 0;
        f32x4 ta = {}, tb = {};
#pragma unroll
        for (int kk = 0; kk < 4; ++kk) {
            const int ko = kk * 32 + q * 8;
            const s16x8 av  = *(const s16x8*)&sab[am * 128 + ko];
            const s16x8 bv0 = *(const s16x8*)&WmT[(n0)      * 128 + ko];
            const s16x8 bv1 = *(const s16x8*)&WmT[(n0 + 16) * 128 + ko];
            ta = __builtin_amdgcn_mfma_f32_16x16x32_bf16(av, bv0, ta, 0, 0, 0);
            tb = __builtin_amdgcn_mfma_f32_16x16x32_bf16(av, bv1, tb, 0, 0, 0);
        }
        if (q == 0) {
            const int c0 = wave * 32 + l16;
            const int c1 = c0 + 16;
            const float bg0 = bg[c0], bg1 = bg[c1];
            tcv[c0] = ta[0] + bg0;  tiv[c0] = ta[1] + bg0;
            tcv[c1] = tb[0] + bg1;  tiv[c1] = tb[1] + bg1;
        }
    }
    __syncthreads();

    // ---- MFMA node transform, both phases ----
    const unsigned short* WcT = (const unsigned short*)(ws + WS_WCT);
    const unsigned short* WiT = (const unsigned short*)(ws + WS_WIT);
    unsigned short* combined =
        (unsigned short*)(ws + WS_COMB) + (size_t)b * COMB;

#pragma unroll
    for (int phase = 0; phase < 2; ++phase) {
        const int NN   = phase ? NPIX : NCLIN;
        const int xoff = phase ? NCLIN : 0;
        const unsigned short* WT = phase ? WiT : WcT;
        const float* tvv = phase ? tiv : tcv;

        const int r0 = xoff + ((l16      < NN) ? l16      : (NN - 1));
        const int r1 = xoff + ((16 + l16 < NN) ? 16 + l16 : (NN - 1));
        const int r2 = xoff + ((32 + l16 < NN) ? 32 + l16 : (NN - 1));

        f32x4 acc[3][2] = {};
#pragma unroll
        for (int kk = 0; kk < 4; ++kk) {
            const int ko = kk * 32 + q * 8;
            const s16x8 a0 = *(const s16x8*)&xl[r0 * XPAD + ko];
            const s16x8 a1 = *(const s16x8*)&xl[r1 * XPAD + ko];
            const s16x8 a2 = *(const s16x8*)&xl[r2 * XPAD + ko];
            const s16x8 b0 = *(const s16x8*)&WT[(n0)      * 128 + ko];
            const s16x8 b1 = *(const s16x8*)&WT[(n0 + 16) * 128 + ko];
            acc[0][0] = __builtin_amdgcn_mfma_f32_16x16x32_bf16(a0, b0, acc[0][0], 0, 0, 0);
            acc[0][1] = __builtin_amdgcn_mfma_f32_16x16x32_bf16(a0, b1, acc[0][1], 0, 0, 0);
            acc[1][0] = __builtin_amdgcn_mfma_f32_16x16x32_bf16(a1, b0, acc[1][0], 0, 0, 0);
            acc[1][1] = __builtin_amdgcn_mfma_f32_16x16x32_bf16(a1, b1, acc[1][1], 0, 0, 0);
            acc[2][0] = __builtin_amdgcn_mfma_f32_16x16x32_bf16(a2, b0, acc[2][0], 0, 0, 0);
            acc[2][1] = __builtin_amdgcn_mfma_f32_16x16x32_bf16(a2, b1, acc[2][1], 0, 0, 0);
        }

        const float t0 = tvv[wave * 32 + l16];
        const float t1 = tvv[wave * 32 + 16 + l16];

        if (phase == 0) {
#pragma unroll
            for (int rt = 0; rt < 3; ++rt) {
#pragma unroll
                for (int r = 0; r < 4; ++r) {
                    const int node = rt * 16 + q * 4 + r;
                    if (node < NCLIN) {
                        combined[node * 128 + wave * 32 + l16] =
                            bf16_rne(fmaxf(acc[rt][0][r] + t0, 0.f));
                        combined[node * 128 + wave * 32 + 16 + l16] =
                            bf16_rne(fmaxf(acc[rt][1][r] + t1, 0.f));
                    }
                }
            }
        } else {
            float g0 = 0.f, g1 = 0.f;
#pragma unroll
            for (int rt = 0; rt < 3; ++rt) {
#pragma unroll
                for (int r = 0; r < 4; ++r) {
                    const int node = rt * 16 + q * 4 + r;
                    if (node < NPIX) {
                        g0 += fmaxf(acc[rt][0][r] + t0, 0.f);
                        g1 += fmaxf(acc[rt][1][r] + t1, 0.f);
                    }
                }
            }
            g0 += __shfl_xor(g0, 16); g0 += __shfl_xor(g0, 32);
            g1 += __shfl_xor(g1, 16); g1 += __shfl_xor(g1, 32);
            if (q == 0) {
                combined[NCLIN * 128 + wave * 32 + l16] =
                    bf16_rne(g0 * (1.0f / 36.0f));
                combined[NCLIN * 128 + wave * 32 + 16 + l16] =
                    bf16_rne(g1 * (1.0f / 36.0f));
            }
        }
    }
}

// z[ks] = combined[:, kbase:kbase+klen] @ W1[...]  via bf16 MFMA.
// Block 128m x 128n, 2x2 waves each 64m x 64n. Chunk-rotation LDS swizzle
// (chunk' = (chunk + (row>>1)) & 3 on 16B granules) -> conflict-free
// ds_read_b128/ds_write_b128 (8 lanes/bank-group, the b128 minimum).
// Ping-pong double buffer, ONE barrier per 32-K iter. Uneven split-K=8.
// Grid (8,4,8) = 256 blocks = 1/CU.
__global__ __launch_bounds__(256) void k_gemm_mfma(float* __restrict__ ws)
{
    const unsigned short* Abase = (const unsigned short*)(ws + WS_COMB);
    const unsigned short* Bbase = (const unsigned short*)(ws + WS_W1T);
    const int m0    = blockIdx.x * 128;
    const int n0    = blockIdx.y * 128;
    const int ks    = blockIdx.z;
    const int kbase = (ks < 4) ? 640 * ks : 2560 + 608 * (ks - 4);
    const int kit   = (ks < 4) ? 20 : 19;
    float* Z = ws + WS_Z + (size_t)ks * ZSTRIDE;

    // double-buffered: [buf][row*32 + swizzled chunk]
    __shared__ __align__(16) unsigned short As[2][128 * 32];  // 2 x 8 KB
    __shared__ __align__(16) unsigned short Bs[2][128 * 32];  // 2 x 8 KB

    const int t    = threadIdx.x;
    const int wave = t >> 6;
    const int lane = t & 63;
    const int wm   = (wave & 1) * 64;
    const int wn   = (wave >> 1) * 64;
    const int l16  = lane & 15;
    const int q    = lane >> 4;

    // staging: thread t -> row = t>>1 (0..127), chunk pair qb = (t&1)*2
    const int srow = t >> 1;
    const int qb   = (t & 1) * 2;
    const unsigned short* gA = Abase + (size_t)(m0 + srow) * COMB + kbase + qb * 8;
    const unsigned short* gB = Bbase + (size_t)(n0 + srow) * COMB + kbase + qb * 8;
    const int sw0 = srow * 32 + ((qb     + (srow >> 1)) & 3) * 8;
    const int sw1 = srow * 32 + ((qb + 1 + (srow >> 1)) & 3) * 8;

    // per-lane swizzled read offsets (4 m-frag rows, 4 n-frag rows)
    int aoff[4], boff[4];
#pragma unroll
    for (int i = 0; i < 4; ++i) {
        const int Ra = wm + i * 16 + l16;
        aoff[i] = Ra * 32 + ((q + (Ra >> 1)) & 3) * 8;
        const int Rb = wn + i * 16 + l16;
        boff[i] = Rb * 32 + ((q + (Rb >> 1)) & 3) * 8;
    }

    f32x4 acc[4][4] = {};

    // prologue: stage tile 0 into buf 0
    *(uint4*)&As[0][sw0] = *(const uint4*)(gA);
    *(uint4*)&As[0][sw1] = *(const uint4*)(gA + 8);
    *(uint4*)&Bs[0][sw0] = *(const uint4*)(gB);
    *(uint4*)&Bs[0][sw1] = *(const uint4*)(gB + 8);

    int cur = 0;
    for (int it = 0; it < kit; ++it) {
        __syncthreads();   // buf[cur] staged; buf[cur^1] reads (it-1) complete
        if (it + 1 < kit) {
            const int kk  = (it + 1) * 32;
            const int nxt = cur ^ 1;
            *(uint4*)&As[nxt][sw0] = *(const uint4*)(gA + kk);
            *(uint4*)&As[nxt][sw1] = *(const uint4*)(gA + kk + 8);
            *(uint4*)&Bs[nxt][sw0] = *(const uint4*)(gB + kk);
            *(uint4*)&Bs[nxt][sw1] = *(const uint4*)(gB + kk + 8);
        }

        s16x8 af[4], bf[4];
#pragma unroll
        for (int i = 0; i < 4; ++i) af[i] = *(const s16x8*)&As[cur][aoff[i]];
#pragma unroll
        for (int i = 0; i < 4; ++i) bf[i] = *(const s16x8*)&Bs[cur][boff[i]];

#pragma unroll
        for (int i = 0; i < 4; ++i) {
#pragma unroll
            for (int j = 0; j < 4; ++j) {
                acc[i][j] = __builtin_amdgcn_mfma_f32_16x16x32_bf16(
                    af[i], bf[j], acc[i][j], 0, 0, 0);
            }
        }

        cur ^= 1;
    }

    // C/D: col = l16, row = q*4 + r
#pragma unroll
    for (int i = 0; i < 4; ++i) {
#pragma unroll
        for (int r = 0; r < 4; ++r) {
            const int mr = m0 + wm + 16 * i + q * 4 + r;
            float* zr = Z + (size_t)mr * HID + n0 + wn + l16;
#pragma unroll
            for (int j = 0; j < 4; ++j) {
                zr[16 * j] = acc[i][j][r];
            }
        }
    }
}

// 4 batches per block (one per wave).
__global__ __launch_bounds__(256) void k_out(
    const float* __restrict__ b1, const float* __restrict__ W2,
    const float* __restrict__ b2, const float* __restrict__ ws,
    float* __restrict__ out)
{
    const int b = blockIdx.x * 4 + (threadIdx.x >> 6);
    const int l = threadIdx.x & 63;
    const float* z = ws + WS_Z + (size_t)b * HID;
    float s = 0.f;
#pragma unroll
    for (int j = 0; j < 8; ++j) {
        const int h = l + j * 64;
        float acc = b1[h];
#pragma unroll
        for (int p = 0; p < 8; ++p) acc += z[(size_t)p * ZSTRIDE + h];
        acc = fmaxf(acc, 0.f);
        s += acc * W2[h];
    }
#pragma unroll
    for (int off = 32; off > 0; off >>= 1) s += __shfl_down(s, off);
    if (l == 0) out[b] = s + b2[0];
}

extern "C" void kernel_launch(void* const* d_in, const int* in_sizes, int n_in,
                              void* d_out, int out_size, void* d_ws, size_t ws_size,
                              hipStream_t stream) {
    const float* clin  = (const float*)d_in[0];
    const float* img   = (const float*)d_in[1];
    const float* wself = (const float*)d_in[2];
    const float* wmsg  = (const float*)d_in[3];
    const float* bg    = (const float*)d_in[4];
    const float* W1    = (const float*)d_in[5];
    const float* b1    = (const float*)d_in[6];
    const float* W2    = (const float*)d_in[7];
    const float* b2    = (const float*)d_in[8];
    float* ws  = (float*)d_ws;
    float* out = (float*)d_out;

    k_static<<<dim3(79, 8), 256, 0, stream>>>(W1, wself, wmsg, ws);
    k_batch <<<dim3(BATCH), 256, 0, stream>>>(clin, img, bg, ws);
    k_gemm_mfma<<<dim3(8, 4, 8), 256, 0, stream>>>(ws);
    k_out<<<dim3(BATCH / 4), 256, 0, stream>>>(b1, W2, b2, ws, out);
}